// Round 7
// baseline (2602.922 us; speedup 1.0000x reference)
//
#include <hip/hip_runtime.h>
#include <cstdint>
#include <cstddef>

typedef _Float16 f16;
typedef _Float16 f16x4 __attribute__((ext_vector_type(4)));
typedef _Float16 f16x8 __attribute__((ext_vector_type(8)));
typedef float f32x4 __attribute__((ext_vector_type(4)));

#define AS1 __attribute__((address_space(1)))
#define AS3 __attribute__((address_space(3)))

// ---------- sizes ----------
#define SEQ 1024
#define BATCH 128
#define INDIM 256
#define HDIM 512
#define MROWS (SEQ * BATCH)          // 131072
#define NCOLS (3 * HDIM)             // 1536
#define BHDIM (BATCH * HDIM)         // 65536
#define TCHUNK 128
#define CHROWS (TCHUNK * BATCH)      // 16384

// GEMM tile geometry
#define BM 256
#define BN 128
#define BK 32

// workspace layout (bytes); total 506,730,496
#define P32_OFF   0ull                         // [16384][1536] f32 = 100,663,296
#define XHI_OFF   100663296ull                 // [131072][256] f16 = 67,108,864
#define XLO_OFF   167772160ull                 // [131072][256] f16 = 67,108,864
#define Y0HI_OFF  234881024ull                 // [131072][512] f16 = 134,217,728
#define Y0LO_OFF  369098752ull                 // [131072][512] f16 = 134,217,728
#define WHI_OFF   503316480ull                 // [1536][512] f16   = 1,572,864
#define WLO_OFF   504889344ull                 // [1536][512] f16   = 1,572,864
#define BIAS_OFF  506462208ull                 // [1536] f32
#define HST_OFF   506468352ull                 // [65536] f32
#define WS_NEEDED 506730496ull

__device__ __forceinline__ float fast_tanh(float x) {
  return 1.0f - 2.0f / (__expf(2.0f * x) + 1.0f);
}
__device__ __forceinline__ float fast_sigmoid(float x) {
  return 1.0f / (1.0f + __expf(-x));
}

__device__ __forceinline__ void gld16(const void* g, void* l) {
  __builtin_amdgcn_global_load_lds((const AS1 void*)g, (AS3 void*)l, 16, 0, 0);
}

// ---------- f32 -> (hi f16, lo' f16 = (v-hi)*2048) split ----------
__global__ __launch_bounds__(256) void split_kernel(const float* __restrict__ in,
                                                    f16* __restrict__ hi,
                                                    f16* __restrict__ lo, int n4) {
  int stride = gridDim.x * blockDim.x;
  for (int i = blockIdx.x * blockDim.x + threadIdx.x; i < n4; i += stride) {
    float4 v = reinterpret_cast<const float4*>(in)[i];
    f16x4 h4 = {(f16)v.x, (f16)v.y, (f16)v.z, (f16)v.w};
    f16x4 l4 = {(f16)((v.x - (float)h4[0]) * 2048.0f),
                (f16)((v.y - (float)h4[1]) * 2048.0f),
                (f16)((v.z - (float)h4[2]) * 2048.0f),
                (f16)((v.w - (float)h4[3]) * 2048.0f)};
    reinterpret_cast<f16x4*>(hi)[i] = h4;
    reinterpret_cast<f16x4*>(lo)[i] = l4;
  }
}

// ---------- GEMM: P[CHROWS,1536](f32) = (Ahi+Alo/2048).(Whi+Wlo/2048)^T + bias ----------
// 256x128 tile, BK=32, 8 waves (4m x 2n, 64x64 out each). Counted-vmcnt phase schedule
// (T3+T4): A hi/lo in a 3-buffer LDS ring (prefetch depth 2), B hi/lo double-buffered
// (depth 1, issued first each tile so vmcnt(4) retires it). 4 quadrant phases per K-tile,
// each {gld issue | ds_read frags -> barrier -> setprio(1) 12 MFMA setprio(0) -> barrier}.
// Main loop never drains vmcnt to 0. LDS = 3*(16+16)KB + 2*(8+8)KB = 128 KB, 1 block/CU.
__global__ __launch_bounds__(512, 2) void gemm_split_kernel(
    const f16* __restrict__ Ahi, const f16* __restrict__ Alo,
    const f16* __restrict__ Whi, const f16* __restrict__ Wlo,
    const float* __restrict__ bias, float* __restrict__ P, int K) {
  __shared__ f16 sAh[3][BM * BK];
  __shared__ f16 sAl[3][BM * BK];
  __shared__ f16 sBh[2][BN * BK];
  __shared__ f16 sBl[2][BN * BK];

  const int tid = threadIdx.x;
  const int lane = tid & 63;
  const int w = tid >> 6;                 // 8 waves
  const int wm = (w >> 1) * 64;           // 4 m-waves
  const int wn = (w & 1) * 64;            // 2 n-waves

  // XCD-aware bijective swizzle (gridDim.x = 768, %8 == 0), n-block fastest
  const int per = gridDim.x >> 3;
  const int logical = (blockIdx.x & 7) * per + (blockIdx.x >> 3);
  const int nb = logical % (NCOLS / BN);
  const int mb = logical / (NCOLS / BN);
  const long m0 = (long)mb * BM;
  const int n0 = nb * BN;

  const int fr = lane & 15;
  const int fk = (lane >> 4) * 8;

  // staging addresses. Per K-tile: A hi/lo = 16KB each (2 rounds of 8KB), B hi/lo = 8KB
  // (1 round). A round: 8 waves x 1KB; lds byte = r*8192 + w*1024 + lane*16.
  // Row = 64B (32 f16); global source per-lane, LDS dest wave-uniform (+lane*16 by HW).
  const int off = w * 1024 + lane * 16;
  const int arow0 = off >> 6;             // rows 0..127   (round 0)
  const int arow1 = 128 + arow0;          // rows 128..255 (round 1)
  const int colb = off & 63;
  const long K2 = (long)K * 2;            // row stride in bytes
  const long aoff0 = (m0 + arow0) * K2 + colb;
  const long aoff1 = (m0 + arow1) * K2 + colb;
  const long boff  = (n0 + arow0) * K2 + colb;   // B rows 0..127

  f32x4 acc[4][4] = {};
  f32x4 accc[4][4] = {};

  const int NT = K / BK;

#define LDA_H(mf) (*reinterpret_cast<const f16x8*>(&sAh[ra][(wm + (mf)*16 + fr) * BK + fk]))
#define LDA_L(mf) (*reinterpret_cast<const f16x8*>(&sAl[ra][(wm + (mf)*16 + fr) * BK + fk]))
#define LDB_H(nf) (*reinterpret_cast<const f16x8*>(&sBh[rB][(wn + (nf)*16 + fr) * BK + fk]))
#define LDB_L(nf) (*reinterpret_cast<const f16x8*>(&sBl[rB][(wn + (nf)*16 + fr) * BK + fk]))
#define MFMA3(ai, bj, AH, AL, BH, BL)                                                      \
  acc[ai][bj]  = __builtin_amdgcn_mfma_f32_16x16x32_f16((AH), (BH), acc[ai][bj], 0, 0, 0); \
  accc[ai][bj] = __builtin_amdgcn_mfma_f32_16x16x32_f16((AH), (BL), accc[ai][bj], 0, 0, 0);\
  accc[ai][bj] = __builtin_amdgcn_mfma_f32_16x16x32_f16((AL), (BH), accc[ai][bj], 0, 0, 0);
#define STAGE_A(buf, tt)                                                                   \
  do {                                                                                     \
    const long kb = (long)(tt) * (BK * 2);                                                 \
    gld16((const char*)Ahi + aoff0 + kb, (char*)&sAh[buf][0] + w * 1024);                  \
    gld16((const char*)Ahi + aoff1 + kb, (char*)&sAh[buf][0] + 8192 + w * 1024);           \
    gld16((const char*)Alo + aoff0 + kb, (char*)&sAl[buf][0] + w * 1024);                  \
    gld16((const char*)Alo + aoff1 + kb, (char*)&sAl[buf][0] + 8192 + w * 1024);           \
  } while (0)
#define STAGE_B(buf, tt)                                                                   \
  do {                                                                                     \
    const long kb = (long)(tt) * (BK * 2);                                                 \
    gld16((const char*)Whi + boff + kb, (char*)&sBh[buf][0] + w * 1024);                   \
    gld16((const char*)Wlo + boff + kb, (char*)&sBl[buf][0] + w * 1024);                   \
  } while (0)

  // prologue: A(0) [4 loads], B(0) [2], A(1) [4]; wait leaves A(1)'s 4 in flight.
  STAGE_A(0, 0);
  STAGE_B(0, 0);
  STAGE_A(1, 1);
  asm volatile("s_waitcnt vmcnt(4)" ::: "memory");
  __builtin_amdgcn_s_barrier();

  for (int t = 0; t < NT; ++t) {
    const int ra = t % 3;
    const int rB = t & 1;
    const bool pfA = (t + 2) < NT;
    const bool pfB = (t + 1) < NT;

    // -------- P0: issue B(t+1); read af01, bf01; MFMA Q(m01,n01) --------
    if (pfB) STAGE_B((t + 1) & 1, t + 1);
    f16x8 afh0 = LDA_H(0), afh1 = LDA_H(1), afl0 = LDA_L(0), afl1 = LDA_L(1);
    f16x8 bfh0 = LDB_H(0), bfh1 = LDB_H(1), bfl0 = LDB_L(0), bfl1 = LDB_L(1);
    __builtin_amdgcn_s_barrier();
    __builtin_amdgcn_s_setprio(1);
    MFMA3(0, 0, afh0, afl0, bfh0, bfl0);
    MFMA3(0, 1, afh0, afl0, bfh1, bfl1);
    MFMA3(1, 0, afh1, afl1, bfh0, bfl0);
    MFMA3(1, 1, afh1, afl1, bfh1, bfl1);
    __builtin_amdgcn_s_setprio(0);
    __builtin_amdgcn_s_barrier();

    // -------- P1: issue A(t+2) hi; read bf23; MFMA Q(m01,n23) --------
    if (pfA) {
      const long kb = (long)(t + 2) * (BK * 2);
      const int sa = (t + 2) % 3;
      gld16((const char*)Ahi + aoff0 + kb, (char*)&sAh[sa][0] + w * 1024);
      gld16((const char*)Ahi + aoff1 + kb, (char*)&sAh[sa][0] + 8192 + w * 1024);
    }
    f16x8 bfh2 = LDB_H(2), bfh3 = LDB_H(3), bfl2 = LDB_L(2), bfl3 = LDB_L(3);
    __builtin_amdgcn_s_barrier();
    __builtin_amdgcn_s_setprio(1);
    MFMA3(0, 2, afh0, afl0, bfh2, bfl2);
    MFMA3(0, 3, afh0, afl0, bfh3, bfl3);
    MFMA3(1, 2, afh1, afl1, bfh2, bfl2);
    MFMA3(1, 3, afh1, afl1, bfh3, bfl3);
    __builtin_amdgcn_s_setprio(0);
    __builtin_amdgcn_s_barrier();

    // -------- P2: issue A(t+2) lo; read af23 (reuse regs); MFMA Q(m23,n23) --------
    if (pfA) {
      const long kb = (long)(t + 2) * (BK * 2);
      const int sa = (t + 2) % 3;
      gld16((const char*)Alo + aoff0 + kb, (char*)&sAl[sa][0] + w * 1024);
      gld16((const char*)Alo + aoff1 + kb, (char*)&sAl[sa][0] + 8192 + w * 1024);
    }
    afh0 = LDA_H(2); afh1 = LDA_H(3); afl0 = LDA_L(2); afl1 = LDA_L(3);
    __builtin_amdgcn_s_barrier();
    __builtin_amdgcn_s_setprio(1);
    MFMA3(2, 2, afh0, afl0, bfh2, bfl2);
    MFMA3(2, 3, afh0, afl0, bfh3, bfl3);
    MFMA3(3, 2, afh1, afl1, bfh2, bfl2);
    MFMA3(3, 3, afh1, afl1, bfh3, bfl3);
    __builtin_amdgcn_s_setprio(0);
    __builtin_amdgcn_s_barrier();

    // -------- P3: MFMA Q(m23,n01) (bf01 still live); counted tile-end wait --------
    __builtin_amdgcn_s_setprio(1);
    MFMA3(2, 0, afh0, afl0, bfh0, bfl0);
    MFMA3(2, 1, afh0, afl0, bfh1, bfl1);
    MFMA3(3, 0, afh1, afl1, bfh0, bfl0);
    MFMA3(3, 1, afh1, afl1, bfh1, bfl1);
    __builtin_amdgcn_s_setprio(0);
    if (t + 1 < NT) {
      // retire A(t+1)+B(t+1) (oldest 6); leave A(t+2)'s 4 in flight. Tail: drain.
      if (pfA) asm volatile("s_waitcnt vmcnt(4)" ::: "memory");
      else     asm volatile("s_waitcnt vmcnt(0)" ::: "memory");
      __builtin_amdgcn_s_barrier();
    }
  }
#undef STAGE_A
#undef STAGE_B
#undef MFMA3
#undef LDA_H
#undef LDA_L
#undef LDB_H
#undef LDB_L

  // epilogue: C/D layout col = lane&15, row = (lane>>4)*4 + reg
  const int crow = (lane >> 4) * 4;
  const int ccol = lane & 15;
#pragma unroll
  for (int nf = 0; nf < 4; ++nf) {
    int gc = n0 + wn + nf * 16 + ccol;
    float bv = bias[gc];
#pragma unroll
    for (int mf = 0; mf < 4; ++mf) {
      long gr = m0 + wm + mf * 16 + crow;
#pragma unroll
      for (int r = 0; r < 4; ++r) {
        P[(gr + r) * NCOLS + gc] = acc[mf][nf][r] + accc[mf][nf][r] * (1.0f / 2048.0f) + bv;
      }
    }
  }
}

// ---------- BRC scan over one t-chunk: one thread per (b,h) chain ----------
// ALL output pointers are pre-offset by the caller to this chunk's base.
__global__ __launch_bounds__(256) void scan_kernel(
    const float* __restrict__ P, const float* __restrict__ hinit,
    float* __restrict__ hstate, int first,
    const float* __restrict__ wc, const float* __restrict__ wa,
    f16* __restrict__ Yhi, f16* __restrict__ Ylo,   // layer-0 split outputs (or null)
    float* __restrict__ Yf,                          // layer-1 f32 output (or null)
    float* __restrict__ HN) {
  const int j = blockIdx.x * 256 + threadIdx.x;  // 0..65535
  const int hh = j & (HDIM - 1);
  float h = first ? hinit[j] : hstate[j];
  const float wcv = wc[hh];
  const float wav = wa[hh];
  const float* p = P + (long)(j >> 9) * NCOLS + hh;
  long yo = j;
#pragma unroll 4
  for (int t = 0; t < TCHUNK; ++t) {
    float pc = p[0];
    float pa = p[HDIM];
    float ph = p[2 * HDIM];
    float c = fast_sigmoid(fmaf(wcv, h, pc));
    float a = 1.0f + fast_tanh(fmaf(wav, h, pa));
    h = c * h + (1.0f - c) * fast_tanh(fmaf(a, h, ph));
    if (Yhi) {
      f16 hv = (f16)h;
      Yhi[yo] = hv;
      Ylo[yo] = (f16)((h - (float)hv) * 2048.0f);
    }
    if (Yf) Yf[yo] = h;
    yo += BHDIM;
    p += BATCH * NCOLS;
  }
  hstate[j] = h;
  if (HN) HN[j] = h;
}

extern "C" void kernel_launch(void* const* d_in, const int* in_sizes, int n_in,
                              void* d_out, int out_size, void* d_ws, size_t ws_size,
                              hipStream_t stream) {
  const float* x   = (const float*)d_in[0];
  const float* h0  = (const float*)d_in[1];
  const float* Uc0 = (const float*)d_in[2];
  const float* wc0 = (const float*)d_in[3];
  const float* bc0 = (const float*)d_in[4];
  const float* Ua0 = (const float*)d_in[5];
  const float* wa0 = (const float*)d_in[6];
  const float* ba0 = (const float*)d_in[7];
  const float* Uh0 = (const float*)d_in[8];
  const float* bh0 = (const float*)d_in[9];
  const float* Uc1 = (const float*)d_in[10];
  const float* wc1 = (const float*)d_in[11];
  const float* bc1 = (const float*)d_in[12];
  const float* Ua1 = (const float*)d_in[13];
  const float* wa1 = (const float*)d_in[14];
  const float* ba1 = (const float*)d_in[15];
  const float* Uh1 = (const float*)d_in[16];
  const float* bh1 = (const float*)d_in[17];

  if (ws_size < WS_NEEDED) return;

  char* ws = (char*)d_ws;
  float* p32  = (float*)(ws + P32_OFF);
  f16* xhi    = (f16*)(ws + XHI_OFF);
  f16* xlo    = (f16*)(ws + XLO_OFF);
  f16* y0hi   = (f16*)(ws + Y0HI_OFF);
  f16* y0lo   = (f16*)(ws + Y0LO_OFF);
  f16* whi    = (f16*)(ws + WHI_OFF);
  f16* wlo    = (f16*)(ws + WLO_OFF);
  float* bias = (float*)(ws + BIAS_OFF);
  float* hst  = (float*)(ws + HST_OFF);

  float* y1  = (float*)d_out;
  float* hn0 = y1 + (long)SEQ * BHDIM;
  float* hn1 = hn0 + BHDIM;

  const int NCH = SEQ / TCHUNK;  // 8
  const dim3 gemm_grid((CHROWS / BM) * (NCOLS / BN));  // 64*12 = 768, %8==0

  // ---- pre-split x ----
  hipLaunchKernelGGL(split_kernel, dim3(2048), dim3(256), 0, stream, x, xhi, xlo,
                     MROWS * INDIM / 4);

  // ---- layer 0 weights/bias (K=256) ----
  hipLaunchKernelGGL(split_kernel, dim3(128), dim3(256), 0, stream, Uc0,
                     whi + 0 * HDIM * INDIM, wlo + 0 * HDIM * INDIM, HDIM * INDIM / 4);
  hipLaunchKernelGGL(split_kernel, dim3(128), dim3(256), 0, stream, Ua0,
                     whi + 1 * HDIM * INDIM, wlo + 1 * HDIM * INDIM, HDIM * INDIM / 4);
  hipLaunchKernelGGL(split_kernel, dim3(128), dim3(256), 0, stream, Uh0,
                     whi + 2 * HDIM * INDIM, wlo + 2 * HDIM * INDIM, HDIM * INDIM / 4);
  hipMemcpyAsync(bias + 0 * HDIM, bc0, HDIM * sizeof(float), hipMemcpyDeviceToDevice, stream);
  hipMemcpyAsync(bias + 1 * HDIM, ba0, HDIM * sizeof(float), hipMemcpyDeviceToDevice, stream);
  hipMemcpyAsync(bias + 2 * HDIM, bh0, HDIM * sizeof(float), hipMemcpyDeviceToDevice, stream);

  // ---- layer 0: chunked GEMM + scan ----
  for (int tc = 0; tc < NCH; ++tc) {
    hipLaunchKernelGGL(gemm_split_kernel, gemm_grid, dim3(512), 0, stream,
                       xhi + (long)tc * CHROWS * INDIM, xlo + (long)tc * CHROWS * INDIM,
                       whi, wlo, bias, p32, INDIM);
    hipLaunchKernelGGL(scan_kernel, dim3(BHDIM / 256), dim3(256), 0, stream,
                       p32, h0, hst, (tc == 0) ? 1 : 0, wc0, wa0,
                       y0hi + (long)tc * TCHUNK * BHDIM, y0lo + (long)tc * TCHUNK * BHDIM,
                       (float*)nullptr, (tc == NCH - 1) ? hn0 : (float*)nullptr);
  }

  // ---- layer 1 weights/bias (K=512) ----
  hipLaunchKernelGGL(split_kernel, dim3(256), dim3(256), 0, stream, Uc1,
                     whi + 0 * HDIM * HDIM, wlo + 0 * HDIM * HDIM, HDIM * HDIM / 4);
  hipLaunchKernelGGL(split_kernel, dim3(256), dim3(256), 0, stream, Ua1,
                     whi + 1 * HDIM * HDIM, wlo + 1 * HDIM * HDIM, HDIM * HDIM / 4);
  hipLaunchKernelGGL(split_kernel, dim3(256), dim3(256), 0, stream, Uh1,
                     whi + 2 * HDIM * HDIM, wlo + 2 * HDIM * HDIM, HDIM * HDIM / 4);
  hipMemcpyAsync(bias + 0 * HDIM, bc1, HDIM * sizeof(float), hipMemcpyDeviceToDevice, stream);
  hipMemcpyAsync(bias + 1 * HDIM, ba1, HDIM * sizeof(float), hipMemcpyDeviceToDevice, stream);
  hipMemcpyAsync(bias + 2 * HDIM, bh1, HDIM * sizeof(float), hipMemcpyDeviceToDevice, stream);

  // ---- layer 1: chunked GEMM + scan ----
  for (int tc = 0; tc < NCH; ++tc) {
    hipLaunchKernelGGL(gemm_split_kernel, gemm_grid, dim3(512), 0, stream,
                       y0hi + (long)tc * CHROWS * HDIM, y0lo + (long)tc * CHROWS * HDIM,
                       whi, wlo, bias, p32, HDIM);
    hipLaunchKernelGGL(scan_kernel, dim3(BHDIM / 256), dim3(256), 0, stream,
                       p32, h0 + BHDIM, hst, (tc == 0) ? 1 : 0, wc1, wa1,
                       (f16*)nullptr, (f16*)nullptr, y1 + (long)tc * TCHUNK * BHDIM,
                       (tc == NCH - 1) ? hn1 : (float*)nullptr);
  }
}

// Round 8
// 2280.507 us; speedup vs baseline: 1.1414x; 1.1414x over previous
//
#include <hip/hip_runtime.h>
#include <cstdint>
#include <cstddef>

typedef _Float16 f16;
typedef _Float16 f16x4 __attribute__((ext_vector_type(4)));
typedef _Float16 f16x8 __attribute__((ext_vector_type(8)));
typedef float f32x4 __attribute__((ext_vector_type(4)));

#define AS1 __attribute__((address_space(1)))
#define AS3 __attribute__((address_space(3)))

// ---------- sizes ----------
#define SEQ 1024
#define BATCH 128
#define INDIM 256
#define HDIM 512
#define MROWS (SEQ * BATCH)          // 131072
#define NCOLS (3 * HDIM)             // 1536
#define BHDIM (BATCH * HDIM)         // 65536
#define TCHUNK 128
#define CHROWS (TCHUNK * BATCH)      // 16384

// workspace layout (bytes); total 506,730,496
#define P32_OFF   0ull                         // [16384][1536] f32 = 100,663,296
#define XHI_OFF   100663296ull                 // [131072][256] f16 = 67,108,864
#define XLO_OFF   167772160ull                 // [131072][256] f16 = 67,108,864
#define Y0HI_OFF  234881024ull                 // [131072][512] f16 = 134,217,728
#define Y0LO_OFF  369098752ull                 // [131072][512] f16 = 134,217,728
#define WHI_OFF   503316480ull                 // [1536][512] f16   = 1,572,864
#define WLO_OFF   504889344ull                 // [1536][512] f16   = 1,572,864
#define BIAS_OFF  506462208ull                 // [1536] f32
#define HST_OFF   506468352ull                 // [65536] f32
#define WS_NEEDED 506730496ull

__device__ __forceinline__ float fast_tanh(float x) {
  return 1.0f - 2.0f / (__expf(2.0f * x) + 1.0f);
}
__device__ __forceinline__ float fast_sigmoid(float x) {
  return 1.0f / (1.0f + __expf(-x));
}

__device__ __forceinline__ void gld16(const void* g, void* l) {
  __builtin_amdgcn_global_load_lds((const AS1 void*)g, (AS3 void*)l, 16, 0, 0);
}

// ---------- f32 -> (hi f16, lo' f16 = (v-hi)*2048) split ----------
__global__ __launch_bounds__(256) void split_kernel(const float* __restrict__ in,
                                                    f16* __restrict__ hi,
                                                    f16* __restrict__ lo, int n4) {
  int stride = gridDim.x * blockDim.x;
  for (int i = blockIdx.x * blockDim.x + threadIdx.x; i < n4; i += stride) {
    float4 v = reinterpret_cast<const float4*>(in)[i];
    f16x4 h4 = {(f16)v.x, (f16)v.y, (f16)v.z, (f16)v.w};
    f16x4 l4 = {(f16)((v.x - (float)h4[0]) * 2048.0f),
                (f16)((v.y - (float)h4[1]) * 2048.0f),
                (f16)((v.z - (float)h4[2]) * 2048.0f),
                (f16)((v.w - (float)h4[3]) * 2048.0f)};
    reinterpret_cast<f16x4*>(hi)[i] = h4;
    reinterpret_cast<f16x4*>(lo)[i] = l4;
  }
}

// ---------- GEMM: P[CHROWS,1536](f32) = (Ahi+Alo/2048).(Whi+Wlo/2048)^T + bias ----------
// r6 skeleton (128x128 tile, 4 waves, ONE barrier per K-step, 2 blocks/CU) with
// depth-2 A prefetch: A hi/lo in a 3-buffer LDS ring (~2 K-steps of latency cover),
// B hi/lo double-buffered (L2-resident, depth 1 suffices). Tile-end wait is counted
// vmcnt(4): retires A(t+1)+B(t+1), leaves A(t+2)'s 4 loads in flight (never drains
// to 0 in the main loop). LDS = (3+3)*8KB + (2+2)*8KB = 80KB -> 2 blocks/CU.
__global__ __launch_bounds__(256, 2) void gemm_split_kernel(
    const f16* __restrict__ Ahi, const f16* __restrict__ Alo,
    const f16* __restrict__ Whi, const f16* __restrict__ Wlo,
    const float* __restrict__ bias, float* __restrict__ P, int K) {
  constexpr int BK = 32;
  __shared__ f16 sAh[3][128 * BK];
  __shared__ f16 sAl[3][128 * BK];
  __shared__ f16 sBh[2][128 * BK];
  __shared__ f16 sBl[2][128 * BK];

  const int tid = threadIdx.x;
  const int lane = tid & 63;
  const int w = tid >> 6;
  const int wm = (w >> 1) * 64;
  const int wn = (w & 1) * 64;

  // XCD-aware bijective swizzle (gridDim.x = 1536, %8 == 0), n-block fastest
  const int per = gridDim.x >> 3;
  const int logical = (blockIdx.x & 7) * per + (blockIdx.x >> 3);
  const int nb = logical % (NCOLS / 128);
  const int mb = logical / (NCOLS / 128);
  const long m0 = (long)mb * 128;
  const int n0 = nb * 128;

  const int fr = lane & 15;
  const int fk = (lane >> 4) * 8;

  // staging: wave w stages bytes [w*2048, w*2048+2048) of each 8KB tile in 2 rounds of
  // 1KB (64 lanes x 16B). LDS dest is wave-uniform base; HW adds lane*16. Global source
  // is per-lane: row = off>>6 (64B/row), colb = off&63 — matches LDS landing slot.
  const int off0 = w * 2048 + lane * 16;
  const int off1 = off0 + 1024;
  const int row0 = off0 >> 6, colb0 = off0 & 63;
  const int row1 = off1 >> 6, colb1 = off1 & 63;
  const long aoff0 = ((m0 + row0) * (long)K) * 2 + colb0;
  const long aoff1 = ((m0 + row1) * (long)K) * 2 + colb1;
  const long boff0 = ((n0 + row0) * (long)K) * 2 + colb0;
  const long boff1 = ((n0 + row1) * (long)K) * 2 + colb1;
  const int ldsw = w * 2048;

  f32x4 acc[4][4] = {};
  f32x4 accc[4][4] = {};

  const int NT = K / BK;

#define STAGE_A(buf, tt)                                                    \
  do {                                                                      \
    const long kb = (long)(tt) * (BK * 2);                                  \
    char* bAh = (char*)&sAh[(buf)][0] + ldsw;                               \
    char* bAl = (char*)&sAl[(buf)][0] + ldsw;                               \
    gld16((const char*)Ahi + aoff0 + kb, bAh);                              \
    gld16((const char*)Ahi + aoff1 + kb, bAh + 1024);                       \
    gld16((const char*)Alo + aoff0 + kb, bAl);                              \
    gld16((const char*)Alo + aoff1 + kb, bAl + 1024);                      \
  } while (0)
#define STAGE_B(buf, tt)                                                    \
  do {                                                                      \
    const long kb = (long)(tt) * (BK * 2);                                  \
    char* bBh = (char*)&sBh[(buf)][0] + ldsw;                               \
    char* bBl = (char*)&sBl[(buf)][0] + ldsw;                               \
    gld16((const char*)Whi + boff0 + kb, bBh);                              \
    gld16((const char*)Whi + boff1 + kb, bBh + 1024);                       \
    gld16((const char*)Wlo + boff0 + kb, bBl);                              \
    gld16((const char*)Wlo + boff1 + kb, bBl + 1024);                      \
  } while (0)

  // prologue: A(0)[4], B(0)[4], A(1)[4] issued; retire A(0)+B(0), leave A(1) flying.
  STAGE_A(0, 0);
  STAGE_B(0, 0);
  STAGE_A(1, 1);
  asm volatile("s_waitcnt vmcnt(4)" ::: "memory");
  __builtin_amdgcn_s_barrier();

  int ra = 0;  // A ring index for tile t
  for (int t = 0; t < NT; ++t) {
    const int rB = t & 1;
    const bool pfB = (t + 1) < NT;
    const bool pfA = (t + 2) < NT;

    // issue next-tile loads BEFORE compute (B depth-1, A depth-2)
    if (pfB) STAGE_B(rB ^ 1, t + 1);
    if (pfA) {
      const int sa = (ra + 2 >= 3) ? (ra - 1) : (ra + 2);  // (ra+2)%3
      STAGE_A(sa, t + 2);
    }

    f16x8 ah[4], al[4], bh[4], bl[4];
#pragma unroll
    for (int i = 0; i < 4; ++i) {
      ah[i] = *reinterpret_cast<const f16x8*>(&sAh[ra][(wm + i * 16 + fr) * BK + fk]);
      al[i] = *reinterpret_cast<const f16x8*>(&sAl[ra][(wm + i * 16 + fr) * BK + fk]);
      bh[i] = *reinterpret_cast<const f16x8*>(&sBh[rB][(wn + i * 16 + fr) * BK + fk]);
      bl[i] = *reinterpret_cast<const f16x8*>(&sBl[rB][(wn + i * 16 + fr) * BK + fk]);
    }

    __builtin_amdgcn_s_setprio(1);
#pragma unroll
    for (int i = 0; i < 4; ++i)
#pragma unroll
      for (int j = 0; j < 4; ++j) {
        acc[i][j]  = __builtin_amdgcn_mfma_f32_16x16x32_f16(ah[i], bh[j], acc[i][j], 0, 0, 0);
        accc[i][j] = __builtin_amdgcn_mfma_f32_16x16x32_f16(ah[i], bl[j], accc[i][j], 0, 0, 0);
        accc[i][j] = __builtin_amdgcn_mfma_f32_16x16x32_f16(al[i], bh[j], accc[i][j], 0, 0, 0);
      }
    __builtin_amdgcn_s_setprio(0);

    if (pfB) {
      // queue (oldest first): A(t+1)[4], B(t+1)[4], A(t+2)[4 if pfA].
      // Retire A(t+1)+B(t+1); keep A(t+2) in flight (counted, not drained).
      if (pfA) asm volatile("s_waitcnt vmcnt(4)" ::: "memory");
      else     asm volatile("s_waitcnt vmcnt(0)" ::: "memory");
      __builtin_amdgcn_s_barrier();
      ra = (ra + 1 >= 3) ? 0 : (ra + 1);
    }
  }
#undef STAGE_A
#undef STAGE_B

  // epilogue: C/D layout col = lane&15, row = (lane>>4)*4 + reg
  const int crow = (lane >> 4) * 4;
  const int ccol = lane & 15;
#pragma unroll
  for (int j = 0; j < 4; ++j) {
    int gc = n0 + wn + j * 16 + ccol;
    float bv = bias[gc];
#pragma unroll
    for (int i = 0; i < 4; ++i) {
      long gr = m0 + wm + i * 16 + crow;
#pragma unroll
      for (int r = 0; r < 4; ++r) {
        P[(gr + r) * NCOLS + gc] = acc[i][j][r] + accc[i][j][r] * (1.0f / 2048.0f) + bv;
      }
    }
  }
}

// ---------- BRC scan over one t-chunk: one thread per (b,h) chain ----------
// ALL output pointers are pre-offset by the caller to this chunk's base.
__global__ __launch_bounds__(256) void scan_kernel(
    const float* __restrict__ P, const float* __restrict__ hinit,
    float* __restrict__ hstate, int first,
    const float* __restrict__ wc, const float* __restrict__ wa,
    f16* __restrict__ Yhi, f16* __restrict__ Ylo,   // layer-0 split outputs (or null)
    float* __restrict__ Yf,                          // layer-1 f32 output (or null)
    float* __restrict__ HN) {
  const int j = blockIdx.x * 256 + threadIdx.x;  // 0..65535
  const int hh = j & (HDIM - 1);
  float h = first ? hinit[j] : hstate[j];
  const float wcv = wc[hh];
  const float wav = wa[hh];
  const float* p = P + (long)(j >> 9) * NCOLS + hh;
  long yo = j;
#pragma unroll 4
  for (int t = 0; t < TCHUNK; ++t) {
    float pc = p[0];
    float pa = p[HDIM];
    float ph = p[2 * HDIM];
    float c = fast_sigmoid(fmaf(wcv, h, pc));
    float a = 1.0f + fast_tanh(fmaf(wav, h, pa));
    h = c * h + (1.0f - c) * fast_tanh(fmaf(a, h, ph));
    if (Yhi) {
      f16 hv = (f16)h;
      Yhi[yo] = hv;
      Ylo[yo] = (f16)((h - (float)hv) * 2048.0f);
    }
    if (Yf) Yf[yo] = h;
    yo += BHDIM;
    p += BATCH * NCOLS;
  }
  hstate[j] = h;
  if (HN) HN[j] = h;
}

extern "C" void kernel_launch(void* const* d_in, const int* in_sizes, int n_in,
                              void* d_out, int out_size, void* d_ws, size_t ws_size,
                              hipStream_t stream) {
  const float* x   = (const float*)d_in[0];
  const float* h0  = (const float*)d_in[1];
  const float* Uc0 = (const float*)d_in[2];
  const float* wc0 = (const float*)d_in[3];
  const float* bc0 = (const float*)d_in[4];
  const float* Ua0 = (const float*)d_in[5];
  const float* wa0 = (const float*)d_in[6];
  const float* ba0 = (const float*)d_in[7];
  const float* Uh0 = (const float*)d_in[8];
  const float* bh0 = (const float*)d_in[9];
  const float* Uc1 = (const float*)d_in[10];
  const float* wc1 = (const float*)d_in[11];
  const float* bc1 = (const float*)d_in[12];
  const float* Ua1 = (const float*)d_in[13];
  const float* wa1 = (const float*)d_in[14];
  const float* ba1 = (const float*)d_in[15];
  const float* Uh1 = (const float*)d_in[16];
  const float* bh1 = (const float*)d_in[17];

  if (ws_size < WS_NEEDED) return;

  char* ws = (char*)d_ws;
  float* p32  = (float*)(ws + P32_OFF);
  f16* xhi    = (f16*)(ws + XHI_OFF);
  f16* xlo    = (f16*)(ws + XLO_OFF);
  f16* y0hi   = (f16*)(ws + Y0HI_OFF);
  f16* y0lo   = (f16*)(ws + Y0LO_OFF);
  f16* whi    = (f16*)(ws + WHI_OFF);
  f16* wlo    = (f16*)(ws + WLO_OFF);
  float* bias = (float*)(ws + BIAS_OFF);
  float* hst  = (float*)(ws + HST_OFF);

  float* y1  = (float*)d_out;
  float* hn0 = y1 + (long)SEQ * BHDIM;
  float* hn1 = hn0 + BHDIM;

  const int NCH = SEQ / TCHUNK;  // 8
  const dim3 gemm_grid(CHROWS / 128 * (NCOLS / 128));  // 1536, %8==0

  // ---- pre-split x ----
  hipLaunchKernelGGL(split_kernel, dim3(2048), dim3(256), 0, stream, x, xhi, xlo,
                     MROWS * INDIM / 4);

  // ---- layer 0 weights/bias (K=256) ----
  hipLaunchKernelGGL(split_kernel, dim3(128), dim3(256), 0, stream, Uc0,
                     whi + 0 * HDIM * INDIM, wlo + 0 * HDIM * INDIM, HDIM * INDIM / 4);
  hipLaunchKernelGGL(split_kernel, dim3(128), dim3(256), 0, stream, Ua0,
                     whi + 1 * HDIM * INDIM, wlo + 1 * HDIM * INDIM, HDIM * INDIM / 4);
  hipLaunchKernelGGL(split_kernel, dim3(128), dim3(256), 0, stream, Uh0,
                     whi + 2 * HDIM * INDIM, wlo + 2 * HDIM * INDIM, HDIM * INDIM / 4);
  hipMemcpyAsync(bias + 0 * HDIM, bc0, HDIM * sizeof(float), hipMemcpyDeviceToDevice, stream);
  hipMemcpyAsync(bias + 1 * HDIM, ba0, HDIM * sizeof(float), hipMemcpyDeviceToDevice, stream);
  hipMemcpyAsync(bias + 2 * HDIM, bh0, HDIM * sizeof(float), hipMemcpyDeviceToDevice, stream);

  // ---- layer 0: chunked GEMM + scan ----
  for (int tc = 0; tc < NCH; ++tc) {
    hipLaunchKernelGGL(gemm_split_kernel, gemm_grid, dim3(256), 0, stream,
                       xhi + (long)tc * CHROWS * INDIM, xlo + (long)tc * CHROWS * INDIM,
                       whi, wlo, bias, p32, INDIM);
    hipLaunchKernelGGL(scan_kernel, dim3(BHDIM / 256), dim3(256), 0, stream,
                       p32, h0, hst, (tc == 0) ? 1 : 0, wc0, wa0,
                       y0hi + (long)tc * TCHUNK * BHDIM, y0lo + (long)tc * TCHUNK * BHDIM,
                       (float*)nullptr, (tc == NCH - 1) ? hn0 : (float*)nullptr);
  }

  // ---- layer 1 weights/bias (K=512) ----
  hipLaunchKernelGGL(split_kernel, dim3(256), dim3(256), 0, stream, Uc1,
                     whi + 0 * HDIM * HDIM, wlo + 0 * HDIM * HDIM, HDIM * HDIM / 4);
  hipLaunchKernelGGL(split_kernel, dim3(256), dim3(256), 0, stream, Ua1,
                     whi + 1 * HDIM * HDIM, wlo + 1 * HDIM * HDIM, HDIM * HDIM / 4);
  hipLaunchKernelGGL(split_kernel, dim3(256), dim3(256), 0, stream, Uh1,
                     whi + 2 * HDIM * HDIM, wlo + 2 * HDIM * HDIM, HDIM * HDIM / 4);
  hipMemcpyAsync(bias + 0 * HDIM, bc1, HDIM * sizeof(float), hipMemcpyDeviceToDevice, stream);
  hipMemcpyAsync(bias + 1 * HDIM, ba1, HDIM * sizeof(float), hipMemcpyDeviceToDevice, stream);
  hipMemcpyAsync(bias + 2 * HDIM, bh1, HDIM * sizeof(float), hipMemcpyDeviceToDevice, stream);

  // ---- layer 1: chunked GEMM + scan ----
  for (int tc = 0; tc < NCH; ++tc) {
    hipLaunchKernelGGL(gemm_split_kernel, gemm_grid, dim3(256), 0, stream,
                       y0hi + (long)tc * CHROWS * HDIM, y0lo + (long)tc * CHROWS * HDIM,
                       whi, wlo, bias, p32, HDIM);
    hipLaunchKernelGGL(scan_kernel, dim3(BHDIM / 256), dim3(256), 0, stream,
                       p32, h0 + BHDIM, hst, (tc == 0) ? 1 : 0, wc1, wa1,
                       (f16*)nullptr, (f16*)nullptr, y1 + (long)tc * TCHUNK * BHDIM,
                       (tc == NCH - 1) ? hn1 : (float*)nullptr);
  }
}